// Round 8
// baseline (37.125 us; speedup 1.0000x reference)
//
#include <hip/hip_runtime.h>

#define TILE  128  // positions per block
#define LS    131  // LDS row stride: 131%32=3 -> conflict-free writes, ~2-way scalar reads
#define OUTCH 87   // 2 coord + 80 scores + 4 bbox + 1 ctr

typedef float f32x4 __attribute__((ext_vector_type(4)));

__global__ __launch_bounds__(512) void fcos_filter_kernel(
    const float* __restrict__ cl0, const float* __restrict__ bb0, const float* __restrict__ ct0,
    const float* __restrict__ cl1, const float* __restrict__ bb1, const float* __restrict__ ct1,
    const float* __restrict__ cl2, const float* __restrict__ bb2, const float* __restrict__ ct2,
    const float* __restrict__ cl3, const float* __restrict__ bb3, const float* __restrict__ ct3,
    const float* __restrict__ cl4, const float* __restrict__ bb4, const float* __restrict__ ct4,
    float* __restrict__ out)
{
    __shared__ float lds[85 * LS];    // 44,540 B
    __shared__ float s_flag[TILE];    // +512 B -> 3 blocks/CU, 24 waves (75%)

    const int bid = blockIdx.x;
    const int tid = threadIdx.x;

    // ---- level decode (per-branch constant divisions) ----
    const float *cls, *bbx, *ctr;
    int img, tile, HW, W, str, ksh;
    size_t obase;
    if (bid < 1600)      { cls=cl0;bbx=bb0;ctr=ct0;HW=25600;W=160;str=8;  ksh=4;obase=0u;
                           img = bid / 200;            tile = bid - img * 200; }
    else if (bid < 2000) { cls=cl1;bbx=bb1;ctr=ct1;HW=6400; W=80; str=16; ksh=3;obase=17817600u;
                           const int b = bid - 1600;   img = b / 50;  tile = b - img * 50; }
    else if (bid < 2104) { cls=cl2;bbx=bb2;ctr=ct2;HW=1600; W=40; str=32; ksh=2;obase=22272000u;
                           const int b = bid - 2000;   img = b / 13;  tile = b - img * 13; }
    else if (bid < 2136) { cls=cl3;bbx=bb3;ctr=ct3;HW=400;  W=20; str=64; ksh=1;obase=23385600u;
                           const int b = bid - 2104;   img = b >> 2;  tile = b & 3; }
    else                 { cls=cl4;bbx=bb4;ctr=ct4;HW=100;  W=10; str=128;ksh=0;obase=23664000u;
                           img = bid - 2136;           tile = 0; }

    const int p0    = tile * TILE;
    const int valid = min(TILE, HW - p0);   // 128,64,16,100 possible

    // ---- Phase A: loads; wave-local mapping (all 80 cls channels inside a wave) ----
    const int w    = tid >> 6;              // wave 0..7, owns positions 16w..16w+15
    const int lane = tid & 63;
    const int r16  = lane >> 2;             // channel group 0..15
    const int q4   = (lane & 3) << 2;       // quad offset 0,4,8,12
    const int pos  = 16 * w + q4;           // first of this thread's 4 positions
    const bool ok  = pos < valid;

    float4 v[5];
    float4 fm; fm.x = fm.y = fm.z = fm.w = -1e30f;
    if (ok) {
        const float* ab = cls + ((size_t)img * 80 + r16) * HW + p0 + pos;
        #pragma unroll
        for (int k = 0; k < 5; ++k) {
            v[k] = *reinterpret_cast<const float4*>(ab + (size_t)(16 * k) * HW);
            fm.x = fmaxf(fm.x, v[k].x);
            fm.y = fmaxf(fm.y, v[k].y);
            fm.z = fmaxf(fm.z, v[k].z);
            fm.w = fmaxf(fm.w, v[k].w);
        }
    }
    // bbox/ctr: 5 rows x 128 pos = 160 float4s, tid<160
    float4 v5;
    const int c5   = tid >> 5;              // 0..4 (only used when tid<160)
    const int pos5 = (tid & 31) << 2;       // 0..124
    const bool ok5 = (tid < 160) && (pos5 < valid);
    if (ok5) {
        const float* s5 = (c5 < 4)
            ? bbx + ((size_t)img * 4 + c5) * HW + p0 + pos5
            : ctr + (size_t)img * HW + p0 + pos5;
        v5 = *reinterpret_cast<const float4*>(s5);
    }

    // ---- LDS writes ----
    if (ok) {
        #pragma unroll
        for (int k = 0; k < 5; ++k) {
            const int a = (16 * k + r16) * LS + pos;
            lds[a + 0] = v[k].x; lds[a + 1] = v[k].y;
            lds[a + 2] = v[k].z; lds[a + 3] = v[k].w;
        }
    }
    if (ok5) {
        const int a = (80 + c5) * LS + pos5;
        lds[a + 0] = v5.x; lds[a + 1] = v5.y;
        lds[a + 2] = v5.z; lds[a + 3] = v5.w;
    }

    // ---- wave-local flag reduce: combine the 16 channel groups (xor 4,8,16,32) ----
    #pragma unroll
    for (int m = 4; m <= 32; m <<= 1) {
        fm.x = fmaxf(fm.x, __shfl_xor(fm.x, m));
        fm.y = fmaxf(fm.y, __shfl_xor(fm.y, m));
        fm.z = fmaxf(fm.z, __shfl_xor(fm.z, m));
        fm.w = fmaxf(fm.w, __shfl_xor(fm.w, m));
    }
    if (lane < 4) {                          // lane l holds q4 = 4l -> positions 16w+4l+0..3
        const int fp = 16 * w + 4 * lane;
        s_flag[fp + 0] = (fm.x > 0.5f) ? 1.0f : 0.0f;
        s_flag[fp + 1] = (fm.y > 0.5f) ? 1.0f : 0.0f;
        s_flag[fp + 2] = (fm.z > 0.5f) ? 1.0f : 0.0f;
        s_flag[fp + 3] = (fm.w > 0.5f) ? 1.0f : 0.0f;
    }

    __syncthreads();                         // the ONLY barrier

    // ---- Phase C: LDS -> global, float4 stores over contiguous valid*87 chunk ----
    float* dst = out + obase + ((size_t)img * HW + p0) * OUTCH;
    const int nmax = valid * OUTCH;          // always divisible by 4 here
    #pragma unroll
    for (int r = 0; r < 6; ++r) {
        const int f4 = tid + 512 * r;
        if (r == 5 && f4 >= (TILE * OUTCH) / 4) break;
        const int e0 = f4 * 4;
        if (e0 >= nmax) break;
        const int p  = e0 / OUTCH;           // magic-mul div by 87
        const int ch = e0 - p * OUTCH;
        float vals[4];
        #pragma unroll
        for (int j = 0; j < 4; ++j) {
            int chj = ch + j, pj = p;
            if (chj >= OUTCH) { chj -= OUTCH; pj += 1; }
            const float m = s_flag[pj];
            float val;
            if (chj >= 2) {
                val = lds[(chj - 2) * LS + pj] * m;
            } else {
                const int pg = p0 + pj;
                const int tt = pg >> ksh;    // = pg / (W/10)
                const int y  = tt / 10;      // magic-mul div by 10
                const int x  = pg - y * W;
                val = (float)(((chj == 0) ? x : y) * str + (str >> 1)) * m;
            }
            vals[j] = val;
        }
        if (e0 + 4 <= nmax) {
            f32x4 o; o.x = vals[0]; o.y = vals[1]; o.z = vals[2]; o.w = vals[3];
            *reinterpret_cast<f32x4*>(dst + e0) = o;
        } else {
            #pragma unroll
            for (int j = 0; j < 4; ++j)
                if (e0 + j < nmax) dst[e0 + j] = vals[j];
        }
    }
}

extern "C" void kernel_launch(void* const* d_in, const int* in_sizes, int n_in,
                              void* d_out, int out_size, void* d_ws, size_t ws_size,
                              hipStream_t stream) {
    (void)in_sizes; (void)n_in; (void)out_size; (void)d_ws; (void)ws_size;
    fcos_filter_kernel<<<2144, 512, 0, stream>>>(
        (const float*)d_in[0],  (const float*)d_in[1],  (const float*)d_in[2],
        (const float*)d_in[3],  (const float*)d_in[4],  (const float*)d_in[5],
        (const float*)d_in[6],  (const float*)d_in[7],  (const float*)d_in[8],
        (const float*)d_in[9],  (const float*)d_in[10], (const float*)d_in[11],
        (const float*)d_in[12], (const float*)d_in[13], (const float*)d_in[14],
        (float*)d_out);
}

// Round 9
// 35.647 us; speedup vs baseline: 1.0415x; 1.0415x over previous
//
#include <hip/hip_runtime.h>

#define NCH   85   // 80 cls + 4 bbox + 1 ctr
#define TILE  64   // positions per block
#define LS    67   // LDS row stride: 67%32=3, odd -> conflict-free A-writes and C-reads
#define OUTCH 87   // 2 coord + 80 scores + 4 bbox + 1 ctr

__global__ __launch_bounds__(256) void fcos_filter_kernel(
    const float* __restrict__ c0, const float* __restrict__ b0, const float* __restrict__ t0,
    const float* __restrict__ c1, const float* __restrict__ b1, const float* __restrict__ t1,
    const float* __restrict__ c2, const float* __restrict__ b2, const float* __restrict__ t2,
    const float* __restrict__ c3, const float* __restrict__ b3, const float* __restrict__ t3,
    const float* __restrict__ c4, const float* __restrict__ b4, const float* __restrict__ t4,
    float* __restrict__ out)
{
    __shared__ float lds[NCH * LS];   // 85*67*4 = 22,780 B
    __shared__ float s_flag[TILE];    // +256 B

    // T1: XCD-chunked bijective swizzle. Grid 4272 = 8 XCDs * 534.
    // HW round-robins blockIdx across XCDs; this gives each XCD a CONTIGUOUS
    // logical range -> per-L2 sequential read/write streams.
    const int bhw = blockIdx.x;
    const int bid = (bhw & 7) * 534 + (bhw >> 3);
    const int tid = threadIdx.x;

    // ---- level decode; img/tile divisions are by per-branch constants ----
    const float *cls, *bbx, *ctr;
    int img, tile, HW, W, str, ksh;
    size_t obase;
    if (bid < 3200)      { cls=c0; bbx=b0; ctr=t0; HW=25600; W=160; str=8;   ksh=4; obase=0u;
                           img = bid / 400;          tile = bid - img * 400; }
    else if (bid < 4000) { cls=c1; bbx=b1; ctr=t1; HW=6400;  W=80;  str=16;  ksh=3; obase=17817600u;
                           const int bl = bid - 3200; img = bl / 100; tile = bl - img * 100; }
    else if (bid < 4200) { cls=c2; bbx=b2; ctr=t2; HW=1600;  W=40;  str=32;  ksh=2; obase=22272000u;
                           const int bl = bid - 4000; img = bl / 25;  tile = bl - img * 25; }
    else if (bid < 4256) { cls=c3; bbx=b3; ctr=t3; HW=400;   W=20;  str=64;  ksh=1; obase=23385600u;
                           const int bl = bid - 4200; img = bl / 7;   tile = bl - img * 7; }
    else                 { cls=c4; bbx=b4; ctr=t4; HW=100;   W=10;  str=128; ksh=0; obase=23664000u;
                           const int bl = bid - 4256; img = bl >> 1;  tile = bl & 1; }

    const int p0    = tile * TILE;
    const int valid = min(TILE, HW - p0);   // <64 only in level 3/4 tail blocks

    // ---- Phase A: global -> LDS; per-thread cls max in registers ----
    const int  lane_c = tid >> 4;           // 0..15
    const int  q4     = (tid & 15) << 2;    // 0,4,...,60
    const bool qok    = q4 < valid;

    float4 v0, v1, v2, v3, v4, v5;
    float4 fm = make_float4(-1e30f, -1e30f, -1e30f, -1e30f);
    const float* abase = cls + ((size_t)img * 80 + lane_c) * HW + p0 + q4;
    if (qok) {
        v0 = *reinterpret_cast<const float4*>(abase);
        v1 = *reinterpret_cast<const float4*>(abase + (size_t)16 * HW);
        v2 = *reinterpret_cast<const float4*>(abase + (size_t)32 * HW);
        v3 = *reinterpret_cast<const float4*>(abase + (size_t)48 * HW);
        v4 = *reinterpret_cast<const float4*>(abase + (size_t)64 * HW);
        fm.x = fmaxf(fmaxf(fmaxf(v0.x, v1.x), fmaxf(v2.x, v3.x)), v4.x);
        fm.y = fmaxf(fmaxf(fmaxf(v0.y, v1.y), fmaxf(v2.y, v3.y)), v4.y);
        fm.z = fmaxf(fmaxf(fmaxf(v0.z, v1.z), fmaxf(v2.z, v3.z)), v4.z);
        fm.w = fmaxf(fmaxf(fmaxf(v0.w, v1.w), fmaxf(v2.w, v3.w)), v4.w);
    }
    const bool r5 = (tid < 80) && qok;      // channels 80..84 (bbox, ctr)
    if (r5) {
        const float* s5 = (lane_c < 4)
            ? bbx + ((size_t)img * 4 + lane_c) * HW + p0 + q4
            : ctr + (size_t)img * HW + p0 + q4;
        v5 = *reinterpret_cast<const float4*>(s5);
    }

    #define PUT(base_c, V)                                          \
    {   const int a = (base_c + lane_c) * LS + q4;                  \
        lds[a + 0] = V.x; lds[a + 1] = V.y;                         \
        lds[a + 2] = V.z; lds[a + 3] = V.w;                         \
    }
    if (qok) { PUT(0, v0) PUT(16, v1) PUT(32, v2) PUT(48, v3) PUT(64, v4) }
    if (r5)  { PUT(80, v5) }
    #undef PUT

    // wave-level reduce of fm across the 4 lane_c groups in this wave
    fm.x = fmaxf(fm.x, __shfl_xor(fm.x, 16));
    fm.y = fmaxf(fm.y, __shfl_xor(fm.y, 16));
    fm.z = fmaxf(fm.z, __shfl_xor(fm.z, 16));
    fm.w = fmaxf(fm.w, __shfl_xor(fm.w, 16));
    fm.x = fmaxf(fm.x, __shfl_xor(fm.x, 32));
    fm.y = fmaxf(fm.y, __shfl_xor(fm.y, 32));
    fm.z = fmaxf(fm.z, __shfl_xor(fm.z, 32));
    fm.w = fmaxf(fm.w, __shfl_xor(fm.w, 32));

    if (tid < TILE) s_flag[tid] = 0.0f;     // before barrier1: safe vs flag writes
    __syncthreads();

    // one set of flag writers per wave (lanes 0..15), cross-wave OR via same-addr stores
    if ((tid & 63) < 16) {
        if (fm.x > 0.5f) s_flag[q4 + 0] = 1.0f;
        if (fm.y > 0.5f) s_flag[q4 + 1] = 1.0f;
        if (fm.z > 0.5f) s_flag[q4 + 2] = 1.0f;
        if (fm.w > 0.5f) s_flag[q4 + 3] = 1.0f;
    }
    __syncthreads();

    // ---- Phase C: LDS -> global, scalar stores over the contiguous chunk ----
    float* dst = out + obase + ((size_t)img * HW + p0) * OUTCH;
    const int nmax = valid * OUTCH;
    #pragma unroll 4
    for (int e = tid; e < TILE * OUTCH; e += 256) {
        const int p  = e / OUTCH;             // magic-mul div by 87
        if (p >= valid) break;
        const int ch = e - p * OUTCH;
        const float m = s_flag[p];
        float val;
        if (ch >= 2) {
            val = lds[(ch - 2) * LS + p] * m;
        } else {
            const int pg = p0 + p;
            const int t  = pg >> ksh;         // = pg / (W/10)
            const int y  = t / 10;            // magic-mul div by 10
            const int x  = pg - y * W;
            const int coord = (ch == 0) ? x : y;
            val = (float)(coord * str + (str >> 1)) * m;
        }
        __builtin_nontemporal_store(val, dst + e);
    }
    (void)nmax;
}

extern "C" void kernel_launch(void* const* d_in, const int* in_sizes, int n_in,
                              void* d_out, int out_size, void* d_ws, size_t ws_size,
                              hipStream_t stream) {
    (void)in_sizes; (void)n_in; (void)out_size; (void)d_ws; (void)ws_size;
    fcos_filter_kernel<<<4272, 256, 0, stream>>>(
        (const float*)d_in[0],  (const float*)d_in[1],  (const float*)d_in[2],
        (const float*)d_in[3],  (const float*)d_in[4],  (const float*)d_in[5],
        (const float*)d_in[6],  (const float*)d_in[7],  (const float*)d_in[8],
        (const float*)d_in[9],  (const float*)d_in[10], (const float*)d_in[11],
        (const float*)d_in[12], (const float*)d_in[13], (const float*)d_in[14],
        (float*)d_out);
}

// Round 10
// 34.984 us; speedup vs baseline: 1.0612x; 1.0190x over previous
//
#include <hip/hip_runtime.h>

#define OUTCH 87        // 2 coord + 80 scores + 4 bbox + 1 ctr
#define WPOS  8         // positions per wave
#define WWORDS 704      // 8*87 data + 8 flag words per wave (2816 B)

typedef float f32x4 __attribute__((ext_vector_type(4)));

// Wave-autonomous: NO __syncthreads anywhere. Each wave stages its 8-position
// tile in a wave-private LDS slice already in OUTPUT layout (mask pre-applied),
// then does a pure linear LDS->global copy.
__global__ __launch_bounds__(256) void fcos_filter_kernel(
    const float* __restrict__ cl0, const float* __restrict__ bb0, const float* __restrict__ ct0,
    const float* __restrict__ cl1, const float* __restrict__ bb1, const float* __restrict__ ct1,
    const float* __restrict__ cl2, const float* __restrict__ bb2, const float* __restrict__ ct2,
    const float* __restrict__ cl3, const float* __restrict__ bb3, const float* __restrict__ ct3,
    const float* __restrict__ cl4, const float* __restrict__ bb4, const float* __restrict__ ct4,
    float* __restrict__ out)
{
    __shared__ float lds[4 * WWORDS];        // 11,264 B -> occupancy capped by waves (32/CU)

    const int tid  = threadIdx.x;
    const int wv   = tid >> 6;
    const int lane = tid & 63;
    float* wlds  = lds + wv * WWORDS;        // wave-private tile, rows of 87
    float* wflag = wlds + 696;               // 8 mask floats

    const int gw = blockIdx.x * 4 + wv;      // global wave id, 0..34103

    // ---- per-wave level decode (const-div per branch) ----
    const float *cls, *bbx, *ctr;
    int img, wi, HW, W, str, ksh;
    size_t obase;
    if (gw < 25600)      { cls=cl0;bbx=bb0;ctr=ct0;HW=25600;W=160;str=8;  ksh=4;obase=0u;
                           img = gw / 3200;          wi = gw - img * 3200; }
    else if (gw < 32000) { cls=cl1;bbx=bb1;ctr=ct1;HW=6400; W=80; str=16; ksh=3;obase=17817600u;
                           const int t = gw - 25600; img = t / 800;  wi = t - img * 800; }
    else if (gw < 33600) { cls=cl2;bbx=bb2;ctr=ct2;HW=1600; W=40; str=32; ksh=2;obase=22272000u;
                           const int t = gw - 32000; img = t / 200;  wi = t - img * 200; }
    else if (gw < 34000) { cls=cl3;bbx=bb3;ctr=ct3;HW=400;  W=20; str=64; ksh=1;obase=23385600u;
                           const int t = gw - 33600; img = t / 50;   wi = t - img * 50; }
    else                 { cls=cl4;bbx=bb4;ctr=ct4;HW=100;  W=10; str=128;ksh=0;obase=23664000u;
                           const int t = gw - 34000; img = t / 13;   wi = t - img * 13; }

    const int p0    = wi * WPOS;
    const int valid = min(WPOS, HW - p0);    // 8, or 4 (last wave of each L4 image)

    // ---- loads: lane = (channel cb, quad q); quad q covers positions 4q..4q+3 ----
    const int  cb  = lane >> 1;              // 0..31
    const int  q   = lane & 1;
    const bool pok = (4 * q) < valid;
    const size_t posoff = (size_t)(p0 + 4 * q);

    float4 v0, v1, v2;
    float4 fm; fm.x = fm.y = fm.z = fm.w = -1e30f;
    if (pok) {
        const float* a0 = cls + ((size_t)img * 80 + cb) * HW + posoff;
        v0 = *reinterpret_cast<const float4*>(a0);
        v1 = *reinterpret_cast<const float4*>(a0 + (size_t)32 * HW);
        fm.x = fmaxf(v0.x, v1.x); fm.y = fmaxf(v0.y, v1.y);
        fm.z = fmaxf(v0.z, v1.z); fm.w = fmaxf(v0.w, v1.w);
    }
    const bool r2 = pok && (cb < 21);        // channels 64..84
    if (r2) {
        const int c = 64 + cb;
        const float* s = (c < 80) ? cls + ((size_t)img * 80 + c) * HW
                       : (c < 84) ? bbx + ((size_t)img * 4 + (c - 80)) * HW
                                  : ctr + (size_t)img * HW;
        v2 = *reinterpret_cast<const float4*>(s + posoff);
        if (cb < 16) {                       // only cls channels feed the max
            fm.x = fmaxf(fm.x, v2.x); fm.y = fmaxf(fm.y, v2.y);
            fm.z = fmaxf(fm.z, v2.z); fm.w = fmaxf(fm.w, v2.w);
        }
    }

    // ---- reduce max over channels (lane bits 1..5), quad bit 0 preserved ----
    #pragma unroll
    for (int m = 2; m <= 32; m <<= 1) {
        fm.x = fmaxf(fm.x, __shfl_xor(fm.x, m));
        fm.y = fmaxf(fm.y, __shfl_xor(fm.y, m));
        fm.z = fmaxf(fm.z, __shfl_xor(fm.z, m));
        fm.w = fmaxf(fm.w, __shfl_xor(fm.w, m));
    }
    float4 mk;
    mk.x = (fm.x > 0.5f) ? 1.0f : 0.0f;
    mk.y = (fm.y > 0.5f) ? 1.0f : 0.0f;
    mk.z = (fm.z > 0.5f) ? 1.0f : 0.0f;
    mk.w = (fm.w > 0.5f) ? 1.0f : 0.0f;

    // ---- transpose-write, mask pre-applied; row stride 87 (odd -> 2-way free) ----
    const int r0w = 4 * q * 87;              // row base for this quad
    if (pok) {
        wlds[r0w +   0 + 2 + cb]      = v0.x * mk.x;
        wlds[r0w +  87 + 2 + cb]      = v0.y * mk.y;
        wlds[r0w + 174 + 2 + cb]      = v0.z * mk.z;
        wlds[r0w + 261 + 2 + cb]      = v0.w * mk.w;
        wlds[r0w +   0 + 34 + cb]     = v1.x * mk.x;   // 2+32+cb
        wlds[r0w +  87 + 34 + cb]     = v1.y * mk.y;
        wlds[r0w + 174 + 34 + cb]     = v1.z * mk.z;
        wlds[r0w + 261 + 34 + cb]     = v1.w * mk.w;
    }
    if (r2) {
        wlds[r0w +   0 + 66 + cb]     = v2.x * mk.x;   // 2+64+cb
        wlds[r0w +  87 + 66 + cb]     = v2.y * mk.y;
        wlds[r0w + 174 + 66 + cb]     = v2.z * mk.z;
        wlds[r0w + 261 + 66 + cb]     = v2.w * mk.w;
    }
    if (lane < 2) {                          // lane == q here; publish quad masks
        f32x4 mo; mo.x = mk.x; mo.y = mk.y; mo.z = mk.z; mo.w = mk.w;
        *reinterpret_cast<f32x4*>(wflag + 4 * lane) = mo;
    }
    if (lane < 8) {                          // coords (in-wave ds RAW order is safe)
        const float m = wflag[lane];
        const int pg = p0 + lane;
        const int t  = pg >> ksh;            // = pg / (W/10)
        const int y  = t / 10;
        const int x  = pg - y * W;
        wlds[lane * 87 + 0] = (float)(x * str + (str >> 1)) * m;
        wlds[lane * 87 + 1] = (float)(y * str + (str >> 1)) * m;
    }

    // ---- store: pure linear LDS -> global copy (no div, no mask) ----
    float* dst = out + obase + ((size_t)img * HW + p0) * OUTCH;
    const int nw = valid * OUTCH;            // 696 or 348, multiple of 4
    {
        const int w = 4 * lane;
        if (w < nw) *reinterpret_cast<f32x4*>(dst + w) = *reinterpret_cast<const f32x4*>(wlds + w);
    }
    {
        const int w = 4 * (lane + 64);
        if (w < nw) *reinterpret_cast<f32x4*>(dst + w) = *reinterpret_cast<const f32x4*>(wlds + w);
    }
    {
        const int w = 4 * (lane + 128);
        if (w < nw) *reinterpret_cast<f32x4*>(dst + w) = *reinterpret_cast<const f32x4*>(wlds + w);
    }
}

extern "C" void kernel_launch(void* const* d_in, const int* in_sizes, int n_in,
                              void* d_out, int out_size, void* d_ws, size_t ws_size,
                              hipStream_t stream) {
    (void)in_sizes; (void)n_in; (void)out_size; (void)d_ws; (void)ws_size;
    // total waves = 25600+6400+1600+400+104 = 34104 = 4 * 8526
    fcos_filter_kernel<<<8526, 256, 0, stream>>>(
        (const float*)d_in[0],  (const float*)d_in[1],  (const float*)d_in[2],
        (const float*)d_in[3],  (const float*)d_in[4],  (const float*)d_in[5],
        (const float*)d_in[6],  (const float*)d_in[7],  (const float*)d_in[8],
        (const float*)d_in[9],  (const float*)d_in[10], (const float*)d_in[11],
        (const float*)d_in[12], (const float*)d_in[13], (const float*)d_in[14],
        (float*)d_out);
}